// Round 7
// baseline (414.429 us; speedup 1.0000x reference)
//
#include <hip/hip_runtime.h>
#include <hip/hip_bf16.h>

// N=2048, D=768, H=12, Y=64. W = [Wq;Wk] as [1536][768].
#define NN 2048
#define DD 768
#define HH 12
#define HW 1536
#define G_ELEMS (NN*DD)           // 1572864
#define W1_ELEMS (HH*64*DD)       // 589824
#define SPLITS 4
#define KPW (NN/SPLITS)           // 512 k-rows per split
#define NCH (KPW/64)              // 8 chunks per split
#define LDP 72                    // 64 + 8 pad -> 2-way max on frag reads (free, m136)
#define NBLK 768                  // 256 CUs x 3 blocks/CU, all co-resident
#define NTHR (NBLK*256)
#define SPIN_BOUND 4000000        // bounded: deadlock -> absmax fail, not hang
#define MAGIC 0xC0FFEEu

typedef __attribute__((ext_vector_type(8))) short bf16x8;
typedef __attribute__((ext_vector_type(4))) float f32x4;

// native v_exp_f32 / v_log_f32 (both base-2). __exp2f/__log2f collide with
// glibc math.h reserved identifiers under -x hip.
__device__ __forceinline__ float exp2g(float x) { return __builtin_amdgcn_exp2f(x); }
__device__ __forceinline__ float log2g(float x) { return __builtin_amdgcn_logf(x); }

// Fold beta*log2(e) = 0.125*1.4426950408889634 into Wq -> scores in base-2.
#define QSCALE 0.18033688011112042f

// Software grid barrier (device scope). Every block: publish stores
// (__syncthreads drains vmcnt; __threadfence writes back this XCD's L2),
// arrive, spin with agent-scope acquire loads, invalidate, rejoin.
__device__ __forceinline__ void gbar(unsigned* bar, int p, int t) {
  __syncthreads();
  if (t == 0) {
    __threadfence();
    __hip_atomic_fetch_add(&bar[16 + p * 16], 1u, __ATOMIC_ACQ_REL,
                           __HIP_MEMORY_SCOPE_AGENT);
    int bound = SPIN_BOUND;
    while (__hip_atomic_load(&bar[16 + p * 16], __ATOMIC_ACQUIRE,
                             __HIP_MEMORY_SCOPE_AGENT) < (unsigned)NBLK &&
           --bound)
      __builtin_amdgcn_s_sleep(2);
    __threadfence();
  }
  __syncthreads();
}

// One kernel, 4 phases separated by gbar():
//   0: fp32->bf16 convert (g, beta-folded Wq, Wk)    [all 768 blocks]
//   1: proj GEMM QK[2048][1536] = gB * wB^T          [blk -> (bm,bn) 32x24]
//   2: scores + per-lane online LSE, split-K         [blk -> (sp,h,qt) 4x12x16]
//   3: merge splits + global sum                     [blocks 0..95]
__global__ __launch_bounds__(256, 3) void mega_kernel(
    const float* __restrict__ g, const float* __restrict__ Wq,
    const float* __restrict__ Wk, __hip_bfloat16* __restrict__ gB,
    __hip_bfloat16* __restrict__ wB, __hip_bfloat16* __restrict__ QK,
    float2* __restrict__ part, unsigned* __restrict__ bar,
    float* __restrict__ out) {
  __shared__ __align__(16) char smem_raw[36864];
  const int t = threadIdx.x;
  const int blk = blockIdx.x;
  const int wave = t >> 6, lane = t & 63;
  const int lr = lane & 15, lg = lane >> 4;
  const int r0 = t >> 3, s0 = (t & 7) * 8;   // staging coords (2 rows/thread)
  const int r1 = r0 + 32;

  // ---- barrier init: counters are 0xAA-poisoned; block 0 zeroes + releases
  if (t == 0) {
    if (blk == 0) {
      __hip_atomic_store(&bar[16], 0u, __ATOMIC_RELAXED, __HIP_MEMORY_SCOPE_AGENT);
      __hip_atomic_store(&bar[32], 0u, __ATOMIC_RELAXED, __HIP_MEMORY_SCOPE_AGENT);
      __hip_atomic_store(&bar[48], 0u, __ATOMIC_RELAXED, __HIP_MEMORY_SCOPE_AGENT);
      out[0] = 0.0f;
      __hip_atomic_store(&bar[0], MAGIC, __ATOMIC_RELEASE, __HIP_MEMORY_SCOPE_AGENT);
    } else {
      int bound = SPIN_BOUND;
      while (__hip_atomic_load(&bar[0], __ATOMIC_ACQUIRE,
                               __HIP_MEMORY_SCOPE_AGENT) != MAGIC && --bound)
        __builtin_amdgcn_s_sleep(2);
    }
  }
  __syncthreads();

  // ---------------- phase 0: convert ----------------
  for (int q4 = blk * 256 + t; q4 < (G_ELEMS + 2 * W1_ELEMS) / 4; q4 += NTHR) {
    int base = q4 * 4;
    float4 v;
    __hip_bfloat16* dst;
    if (base < G_ELEMS) {
      v = *reinterpret_cast<const float4*>(g + base);
      dst = gB + base;
    } else if (base < G_ELEMS + W1_ELEMS) {
      int o = base - G_ELEMS;
      v = *reinterpret_cast<const float4*>(Wq + o);
      v.x *= QSCALE; v.y *= QSCALE; v.z *= QSCALE; v.w *= QSCALE;
      dst = wB + o;
    } else {
      int o = base - (G_ELEMS + W1_ELEMS);
      v = *reinterpret_cast<const float4*>(Wk + o);
      dst = wB + W1_ELEMS + o;
    }
    __hip_bfloat16 h0 = __float2bfloat16(v.x), h1 = __float2bfloat16(v.y);
    __hip_bfloat16 h2 = __float2bfloat16(v.z), h3 = __float2bfloat16(v.w);
    ushort4 u;
    u.x = *reinterpret_cast<unsigned short*>(&h0);
    u.y = *reinterpret_cast<unsigned short*>(&h1);
    u.z = *reinterpret_cast<unsigned short*>(&h2);
    u.w = *reinterpret_cast<unsigned short*>(&h3);
    *reinterpret_cast<ushort4*>(dst) = u;
  }
  gbar(bar, 0, t);

  // ---------------- phase 1: projection GEMM ----------------
  {
    __hip_bfloat16* As = (__hip_bfloat16*)smem_raw;            // [2][64*LDP]
    __hip_bfloat16* Bs = (__hip_bfloat16*)(smem_raw + 18432);  // [2][64*LDP]
    const int wm = wave & 1, wn = wave >> 1;
    const int bm = blk / 24, bn = blk % 24;

    f32x4 acc[2][2] = {};
    // prologue: stage kt=0
    *reinterpret_cast<uint4*>(&As[r0 * LDP + s0]) =
        *reinterpret_cast<const uint4*>(gB + (bm * 64 + r0) * DD + s0);
    *reinterpret_cast<uint4*>(&As[r1 * LDP + s0]) =
        *reinterpret_cast<const uint4*>(gB + (bm * 64 + r1) * DD + s0);
    *reinterpret_cast<uint4*>(&Bs[r0 * LDP + s0]) =
        *reinterpret_cast<const uint4*>(wB + (bn * 64 + r0) * DD + s0);
    *reinterpret_cast<uint4*>(&Bs[r1 * LDP + s0]) =
        *reinterpret_cast<const uint4*>(wB + (bn * 64 + r1) * DD + s0);
    __syncthreads();

    for (int it = 0; it < 12; ++it) {
      const int cur = (it & 1) * 64 * LDP;
      uint4 na0, na1, nb0, nb1;
      if (it < 11) {
        int kt = (it + 1) * 64;
        na0 = *reinterpret_cast<const uint4*>(gB + (bm * 64 + r0) * DD + kt + s0);
        na1 = *reinterpret_cast<const uint4*>(gB + (bm * 64 + r1) * DD + kt + s0);
        nb0 = *reinterpret_cast<const uint4*>(wB + (bn * 64 + r0) * DD + kt + s0);
        nb1 = *reinterpret_cast<const uint4*>(wB + (bn * 64 + r1) * DD + kt + s0);
      }
#pragma unroll
      for (int ks = 0; ks < 2; ++ks) {
        bf16x8 a[2], b[2];
#pragma unroll
        for (int mt = 0; mt < 2; ++mt)
          a[mt] = *reinterpret_cast<const bf16x8*>(&As[cur + (wm * 32 + mt * 16 + lr) * LDP + ks * 32 + lg * 8]);
#pragma unroll
        for (int nt = 0; nt < 2; ++nt)
          b[nt] = *reinterpret_cast<const bf16x8*>(&Bs[cur + (wn * 32 + nt * 16 + lr) * LDP + ks * 32 + lg * 8]);
#pragma unroll
        for (int mt = 0; mt < 2; ++mt)
#pragma unroll
          for (int nt = 0; nt < 2; ++nt)
            acc[mt][nt] = __builtin_amdgcn_mfma_f32_16x16x32_bf16(a[mt], b[nt], acc[mt][nt], 0, 0, 0);
      }
      if (it < 11) {
        const int nxt = cur ^ (64 * LDP);
        *reinterpret_cast<uint4*>(&As[nxt + r0 * LDP + s0]) = na0;
        *reinterpret_cast<uint4*>(&As[nxt + r1 * LDP + s0]) = na1;
        *reinterpret_cast<uint4*>(&Bs[nxt + r0 * LDP + s0]) = nb0;
        *reinterpret_cast<uint4*>(&Bs[nxt + r1 * LDP + s0]) = nb1;
        __syncthreads();
      }
    }
#pragma unroll
    for (int mt = 0; mt < 2; ++mt) {
      int row = bm * 64 + wm * 32 + mt * 16 + lg * 4;
#pragma unroll
      for (int nt = 0; nt < 2; ++nt) {
        int col = bn * 64 + wn * 32 + nt * 16 + lr;
#pragma unroll
        for (int r = 0; r < 4; ++r)
          QK[(row + r) * HW + col] = __float2bfloat16(acc[mt][nt][r]);
      }
    }
  }
  gbar(bar, 1, t);

  // ---------------- phase 2: scores + per-lane online LSE ----------------
  {
    __hip_bfloat16* Ks = (__hip_bfloat16*)smem_raw;            // [2][64*LDP]
    const int rem = blk % 192;
    const int sp = blk / 192, h = rem >> 4, qt = rem & 15;
    const int q0 = qt * 128;
    const int k0 = sp * KPW;
    const int colK = DD + h * 64;

    // Q fragments: 4 direct global loads, resident for the whole phase
    bf16x8 aq[2][2];
#pragma unroll
    for (int mt = 0; mt < 2; ++mt)
#pragma unroll
      for (int z = 0; z < 2; ++z)
        aq[mt][z] = *reinterpret_cast<const bf16x8*>(
            QK + (q0 + wave * 32 + mt * 16 + lr) * HW + h * 64 + z * 32 + lg * 8);

    // prologue: stage chunk 0
    *reinterpret_cast<uint4*>(&Ks[r0 * LDP + s0]) =
        *reinterpret_cast<const uint4*>(QK + (k0 + r0) * HW + colK + s0);
    *reinterpret_cast<uint4*>(&Ks[r1 * LDP + s0]) =
        *reinterpret_cast<const uint4*>(QK + (k0 + r1) * HW + colK + s0);
    __syncthreads();

    float m[2][4], l[2][4];
#pragma unroll
    for (int mt = 0; mt < 2; ++mt)
#pragma unroll
      for (int r = 0; r < 4; ++r) { m[mt][r] = -3.0e38f; l[mt][r] = 0.0f; }

    for (int ci = 0; ci < NCH; ++ci) {
      const int cur = (ci & 1) * 64 * LDP;
      uint4 n0, n1;
      if (ci < NCH - 1) {
        int kc = k0 + (ci + 1) * 64;
        n0 = *reinterpret_cast<const uint4*>(QK + (kc + r0) * HW + colK + s0);
        n1 = *reinterpret_cast<const uint4*>(QK + (kc + r1) * HW + colK + s0);
      }
      bf16x8 b[4][2];
#pragma unroll
      for (int nt = 0; nt < 4; ++nt)
#pragma unroll
        for (int z = 0; z < 2; ++z)
          b[nt][z] = *reinterpret_cast<const bf16x8*>(&Ks[cur + (nt * 16 + lr) * LDP + z * 32 + lg * 8]);

      f32x4 s[2][4] = {};
#pragma unroll
      for (int mt = 0; mt < 2; ++mt)
#pragma unroll
        for (int nt = 0; nt < 4; ++nt)
#pragma unroll
          for (int z = 0; z < 2; ++z)
            s[mt][nt] = __builtin_amdgcn_mfma_f32_16x16x32_bf16(aq[mt][z], b[nt][z], s[mt][nt], 0, 0, 0);

      // per-lane online update (scores already in base-2 units)
#pragma unroll
      for (int mt = 0; mt < 2; ++mt)
#pragma unroll
        for (int r = 0; r < 4; ++r) {
          float v0 = s[mt][0][r], v1 = s[mt][1][r], v2 = s[mt][2][r], v3 = s[mt][3][r];
          float cm = fmaxf(fmaxf(v0, v1), fmaxf(v2, v3));
          float mn = fmaxf(m[mt][r], cm);
          float p = exp2g(v0 - mn) + exp2g(v1 - mn) +
                    exp2g(v2 - mn) + exp2g(v3 - mn);
          l[mt][r] = l[mt][r] * exp2g(m[mt][r] - mn) + p;
          m[mt][r] = mn;
        }
      if (ci < NCH - 1) {
        const int nxt = cur ^ (64 * LDP);
        *reinterpret_cast<uint4*>(&Ks[nxt + r0 * LDP + s0]) = n0;
        *reinterpret_cast<uint4*>(&Ks[nxt + r1 * LDP + s0]) = n1;
        __syncthreads();
      }
    }
    // butterfly merge across the 16 lr-lanes (lg bits untouched)
#pragma unroll
    for (int msk = 1; msk <= 8; msk <<= 1) {
#pragma unroll
      for (int mt = 0; mt < 2; ++mt)
#pragma unroll
        for (int r = 0; r < 4; ++r) {
          float mo = __shfl_xor(m[mt][r], msk);
          float lo = __shfl_xor(l[mt][r], msk);
          float mn = fmaxf(m[mt][r], mo);
          l[mt][r] = l[mt][r] * exp2g(m[mt][r] - mn) + lo * exp2g(mo - mn);
          m[mt][r] = mn;
        }
    }
    if (lr == 0) {
#pragma unroll
      for (int mt = 0; mt < 2; ++mt)
#pragma unroll
        for (int r = 0; r < 4; ++r) {
          int q = q0 + wave * 32 + mt * 16 + lg * 4 + r;
          part[(sp * HH + h) * NN + q] = make_float2(m[mt][r], l[mt][r]);
        }
    }
  }
  gbar(bar, 2, t);

  // ---------------- phase 3: merge splits + global sum ----------------
  if (blk < 96) {
    float* wsum = (float*)smem_raw;
    const int row = blk * 256 + t;                 // 0..24575 = h*2048+q
    float2 p0 = part[row];
    float2 p1 = part[24576 + row];
    float2 p2 = part[49152 + row];
    float2 p3 = part[73728 + row];
    float mm = fmaxf(fmaxf(p0.x, p1.x), fmaxf(p2.x, p3.x));
    float ll = p0.y * exp2g(p0.x - mm) + p1.y * exp2g(p1.x - mm) +
               p2.y * exp2g(p2.x - mm) + p3.y * exp2g(p3.x - mm);
    float lse = mm + log2g(ll);                    // base-2 lse
#pragma unroll
    for (int msk = 1; msk <= 32; msk <<= 1)
      lse += __shfl_xor(lse, msk);
    if (lane == 0) wsum[wave] = lse;
    __syncthreads();
    if (t == 0)
      atomicAdd(out, -5.545177444479562f * (wsum[0] + wsum[1] + wsum[2] + wsum[3]));
  }
}

// ---------------- launch -----------------------------------------------------
extern "C" void kernel_launch(void* const* d_in, const int* in_sizes, int n_in,
                              void* d_out, int out_size, void* d_ws, size_t ws_size,
                              hipStream_t stream) {
  const float* g  = (const float*)d_in[0];
  const float* Wq = (const float*)d_in[1];
  const float* Wk = (const float*)d_in[2];
  float* out = (float*)d_out;

  char* ws = (char*)d_ws;
  __hip_bfloat16* gB = (__hip_bfloat16*)ws;                    // 3.1 MB
  __hip_bfloat16* wB = (__hip_bfloat16*)(ws + 3145728);        // 2.4 MB
  __hip_bfloat16* QK = (__hip_bfloat16*)(ws + 5505024);        // 6.3 MB
  float2* part = (float2*)(ws + 11796480);                     // 786 KB
  unsigned* bar = (unsigned*)(ws + 12582912);                  // barrier state

  mega_kernel<<<NBLK, 256, 0, stream>>>(g, Wq, Wk, gB, wB, QK, part, bar, out);
}

// Round 8
// 345.122 us; speedup vs baseline: 1.2008x; 1.2008x over previous
//
#include <hip/hip_runtime.h>
#include <hip/hip_bf16.h>

// N=2048, D=768, H=12, Y=64. W = [Wq;Wk] as [1536][768].
#define NN 2048
#define DD 768
#define HH 12
#define HW 1536
#define G_ELEMS (NN*DD)           // 1572864
#define W1_ELEMS (HH*64*DD)       // 589824
#define SPLITS 4
#define KPW (NN/SPLITS)           // 512 k-rows per split
#define NCH (KPW/64)              // 8 chunks per split
#define LDP 72                    // 64 + 8 pad
#define NBLK 768                  // 256 CUs x 3 blocks/CU, all co-resident
#define NTHR (NBLK*256)
#define SPIN_BOUND 4000000        // bounded: deadlock -> absmax fail, not hang
#define MAGIC 0xC0FFEEu

typedef __attribute__((ext_vector_type(8))) short bf16x8;
typedef __attribute__((ext_vector_type(4))) float f32x4;

// native v_exp_f32 / v_log_f32 (both base-2). __exp2f/__log2f collide with
// glibc math.h reserved identifiers under -x hip.
__device__ __forceinline__ float exp2g(float x) { return __builtin_amdgcn_exp2f(x); }
__device__ __forceinline__ float log2g(float x) { return __builtin_amdgcn_logf(x); }

// Fold beta*log2(e) = 0.125*1.4426950408889634 into Wq -> scores in base-2.
#define QSCALE 0.18033688011112042f

// Software grid barrier. KEY FIX vs round 7: spin with RELAXED agent-scope
// loads (no per-poll cache invalidate!) and issue ONE acquire fence after
// the spin exits. Release fence before arriving publishes our stores.
__device__ __forceinline__ void gbar(unsigned* cnt, int t) {
  __syncthreads();
  if (t == 0) {
    __threadfence();                              // release: publish stores
    __hip_atomic_fetch_add(cnt, 1u, __ATOMIC_RELAXED, __HIP_MEMORY_SCOPE_AGENT);
    int bound = SPIN_BOUND;
    while (__hip_atomic_load(cnt, __ATOMIC_RELAXED,
                             __HIP_MEMORY_SCOPE_AGENT) < (unsigned)NBLK &&
           --bound)
      __builtin_amdgcn_s_sleep(4);
    __threadfence();                              // acquire: invalidate once
  }
  __syncthreads();
}

// One kernel, 4 phases separated by gbar():
//   0: fp32->bf16 convert (g, beta-folded Wq, Wk)    [all 768 blocks]
//   1: proj GEMM QK[2048][1536] = gB * wB^T          [blk -> (bm,bn) 32x24]
//   2: scores + per-lane online LSE, split-K         [blk -> (sp,h,qt) 4x12x16]
//   3: merge splits + global sum                     [blocks 0..95]
__global__ __launch_bounds__(256, 3) void mega_kernel(
    const float* __restrict__ g, const float* __restrict__ Wq,
    const float* __restrict__ Wk, __hip_bfloat16* __restrict__ gB,
    __hip_bfloat16* __restrict__ wB, __hip_bfloat16* __restrict__ QK,
    float2* __restrict__ part, unsigned* __restrict__ bar,
    float* __restrict__ out) {
  __shared__ __align__(16) char smem_raw[36864];
  const int t = threadIdx.x;
  const int blk = blockIdx.x;
  const int wave = t >> 6, lane = t & 63;
  const int lr = lane & 15, lg = lane >> 4;
  const int r0 = t >> 3, s0 = (t & 7) * 8;   // staging coords (2 rows/thread)
  const int r1 = r0 + 32;

  // ---- barrier init: counters are 0xAA-poisoned; block 0 zeroes + releases.
  // Waiters poll RELAXED (no invalidate storm) then fence once.
  if (t == 0) {
    if (blk == 0) {
      __hip_atomic_store(&bar[16], 0u, __ATOMIC_RELAXED, __HIP_MEMORY_SCOPE_AGENT);
      __hip_atomic_store(&bar[32], 0u, __ATOMIC_RELAXED, __HIP_MEMORY_SCOPE_AGENT);
      __hip_atomic_store(&bar[48], 0u, __ATOMIC_RELAXED, __HIP_MEMORY_SCOPE_AGENT);
      out[0] = 0.0f;
      __threadfence();
      __hip_atomic_store(&bar[0], MAGIC, __ATOMIC_RELAXED, __HIP_MEMORY_SCOPE_AGENT);
    } else {
      int bound = SPIN_BOUND;
      while (__hip_atomic_load(&bar[0], __ATOMIC_RELAXED,
                               __HIP_MEMORY_SCOPE_AGENT) != MAGIC && --bound)
        __builtin_amdgcn_s_sleep(4);
      __threadfence();
    }
  }
  __syncthreads();

  // ---------------- phase 0: convert ----------------
  for (int q4 = blk * 256 + t; q4 < (G_ELEMS + 2 * W1_ELEMS) / 4; q4 += NTHR) {
    int base = q4 * 4;
    float4 v;
    __hip_bfloat16* dst;
    if (base < G_ELEMS) {
      v = *reinterpret_cast<const float4*>(g + base);
      dst = gB + base;
    } else if (base < G_ELEMS + W1_ELEMS) {
      int o = base - G_ELEMS;
      v = *reinterpret_cast<const float4*>(Wq + o);
      v.x *= QSCALE; v.y *= QSCALE; v.z *= QSCALE; v.w *= QSCALE;
      dst = wB + o;
    } else {
      int o = base - (G_ELEMS + W1_ELEMS);
      v = *reinterpret_cast<const float4*>(Wk + o);
      dst = wB + W1_ELEMS + o;
    }
    __hip_bfloat16 h0 = __float2bfloat16(v.x), h1 = __float2bfloat16(v.y);
    __hip_bfloat16 h2 = __float2bfloat16(v.z), h3 = __float2bfloat16(v.w);
    ushort4 u;
    u.x = *reinterpret_cast<unsigned short*>(&h0);
    u.y = *reinterpret_cast<unsigned short*>(&h1);
    u.z = *reinterpret_cast<unsigned short*>(&h2);
    u.w = *reinterpret_cast<unsigned short*>(&h3);
    *reinterpret_cast<ushort4*>(dst) = u;
  }
  gbar(&bar[16], t);

  // ---------------- phase 1: projection GEMM ----------------
  {
    __hip_bfloat16* As = (__hip_bfloat16*)smem_raw;            // [2][64*LDP]
    __hip_bfloat16* Bs = (__hip_bfloat16*)(smem_raw + 18432);  // [2][64*LDP]
    const int wm = wave & 1, wn = wave >> 1;
    const int bm = blk / 24, bn = blk % 24;

    f32x4 acc[2][2] = {};
    // prologue: stage kt=0
    *reinterpret_cast<uint4*>(&As[r0 * LDP + s0]) =
        *reinterpret_cast<const uint4*>(gB + (bm * 64 + r0) * DD + s0);
    *reinterpret_cast<uint4*>(&As[r1 * LDP + s0]) =
        *reinterpret_cast<const uint4*>(gB + (bm * 64 + r1) * DD + s0);
    *reinterpret_cast<uint4*>(&Bs[r0 * LDP + s0]) =
        *reinterpret_cast<const uint4*>(wB + (bn * 64 + r0) * DD + s0);
    *reinterpret_cast<uint4*>(&Bs[r1 * LDP + s0]) =
        *reinterpret_cast<const uint4*>(wB + (bn * 64 + r1) * DD + s0);
    __syncthreads();

    for (int it = 0; it < 12; ++it) {
      const int cur = (it & 1) * 64 * LDP;
      uint4 na0, na1, nb0, nb1;
      if (it < 11) {
        int kt = (it + 1) * 64;
        na0 = *reinterpret_cast<const uint4*>(gB + (bm * 64 + r0) * DD + kt + s0);
        na1 = *reinterpret_cast<const uint4*>(gB + (bm * 64 + r1) * DD + kt + s0);
        nb0 = *reinterpret_cast<const uint4*>(wB + (bn * 64 + r0) * DD + kt + s0);
        nb1 = *reinterpret_cast<const uint4*>(wB + (bn * 64 + r1) * DD + kt + s0);
      }
#pragma unroll
      for (int ks = 0; ks < 2; ++ks) {
        bf16x8 a[2], b[2];
#pragma unroll
        for (int mt = 0; mt < 2; ++mt)
          a[mt] = *reinterpret_cast<const bf16x8*>(&As[cur + (wm * 32 + mt * 16 + lr) * LDP + ks * 32 + lg * 8]);
#pragma unroll
        for (int nt = 0; nt < 2; ++nt)
          b[nt] = *reinterpret_cast<const bf16x8*>(&Bs[cur + (wn * 32 + nt * 16 + lr) * LDP + ks * 32 + lg * 8]);
#pragma unroll
        for (int mt = 0; mt < 2; ++mt)
#pragma unroll
          for (int nt = 0; nt < 2; ++nt)
            acc[mt][nt] = __builtin_amdgcn_mfma_f32_16x16x32_bf16(a[mt], b[nt], acc[mt][nt], 0, 0, 0);
      }
      if (it < 11) {
        const int nxt = cur ^ (64 * LDP);
        *reinterpret_cast<uint4*>(&As[nxt + r0 * LDP + s0]) = na0;
        *reinterpret_cast<uint4*>(&As[nxt + r1 * LDP + s0]) = na1;
        *reinterpret_cast<uint4*>(&Bs[nxt + r0 * LDP + s0]) = nb0;
        *reinterpret_cast<uint4*>(&Bs[nxt + r1 * LDP + s0]) = nb1;
        __syncthreads();
      }
    }
#pragma unroll
    for (int mt = 0; mt < 2; ++mt) {
      int row = bm * 64 + wm * 32 + mt * 16 + lg * 4;
#pragma unroll
      for (int nt = 0; nt < 2; ++nt) {
        int col = bn * 64 + wn * 32 + nt * 16 + lr;
#pragma unroll
        for (int r = 0; r < 4; ++r)
          QK[(row + r) * HW + col] = __float2bfloat16(acc[mt][nt][r]);
      }
    }
  }
  gbar(&bar[32], t);

  // ---------------- phase 2: scores + per-lane online LSE ----------------
  {
    __hip_bfloat16* Ks = (__hip_bfloat16*)smem_raw;            // [2][64*LDP]
    const int rem = blk % 192;
    const int sp = blk / 192, h = rem >> 4, qt = rem & 15;
    const int q0 = qt * 128;
    const int k0 = sp * KPW;
    const int colK = DD + h * 64;

    // Q fragments: 4 direct global loads, resident for the whole phase
    bf16x8 aq[2][2];
#pragma unroll
    for (int mt = 0; mt < 2; ++mt)
#pragma unroll
      for (int z = 0; z < 2; ++z)
        aq[mt][z] = *reinterpret_cast<const bf16x8*>(
            QK + (q0 + wave * 32 + mt * 16 + lr) * HW + h * 64 + z * 32 + lg * 8);

    // prologue: stage chunk 0
    *reinterpret_cast<uint4*>(&Ks[r0 * LDP + s0]) =
        *reinterpret_cast<const uint4*>(QK + (k0 + r0) * HW + colK + s0);
    *reinterpret_cast<uint4*>(&Ks[r1 * LDP + s0]) =
        *reinterpret_cast<const uint4*>(QK + (k0 + r1) * HW + colK + s0);
    __syncthreads();

    float m[2][4], l[2][4];
#pragma unroll
    for (int mt = 0; mt < 2; ++mt)
#pragma unroll
      for (int r = 0; r < 4; ++r) { m[mt][r] = -3.0e38f; l[mt][r] = 0.0f; }

    for (int ci = 0; ci < NCH; ++ci) {
      const int cur = (ci & 1) * 64 * LDP;
      uint4 n0, n1;
      if (ci < NCH - 1) {
        int kc = k0 + (ci + 1) * 64;
        n0 = *reinterpret_cast<const uint4*>(QK + (kc + r0) * HW + colK + s0);
        n1 = *reinterpret_cast<const uint4*>(QK + (kc + r1) * HW + colK + s0);
      }
      bf16x8 b[4][2];
#pragma unroll
      for (int nt = 0; nt < 4; ++nt)
#pragma unroll
        for (int z = 0; z < 2; ++z)
          b[nt][z] = *reinterpret_cast<const bf16x8*>(&Ks[cur + (nt * 16 + lr) * LDP + z * 32 + lg * 8]);

      f32x4 s[2][4] = {};
#pragma unroll
      for (int mt = 0; mt < 2; ++mt)
#pragma unroll
        for (int nt = 0; nt < 4; ++nt)
#pragma unroll
          for (int z = 0; z < 2; ++z)
            s[mt][nt] = __builtin_amdgcn_mfma_f32_16x16x32_bf16(aq[mt][z], b[nt][z], s[mt][nt], 0, 0, 0);

      // per-lane online update (scores already in base-2 units)
#pragma unroll
      for (int mt = 0; mt < 2; ++mt)
#pragma unroll
        for (int r = 0; r < 4; ++r) {
          float v0 = s[mt][0][r], v1 = s[mt][1][r], v2 = s[mt][2][r], v3 = s[mt][3][r];
          float cm = fmaxf(fmaxf(v0, v1), fmaxf(v2, v3));
          float mn = fmaxf(m[mt][r], cm);
          float p = exp2g(v0 - mn) + exp2g(v1 - mn) +
                    exp2g(v2 - mn) + exp2g(v3 - mn);
          l[mt][r] = l[mt][r] * exp2g(m[mt][r] - mn) + p;
          m[mt][r] = mn;
        }
      if (ci < NCH - 1) {
        const int nxt = cur ^ (64 * LDP);
        *reinterpret_cast<uint4*>(&Ks[nxt + r0 * LDP + s0]) = n0;
        *reinterpret_cast<uint4*>(&Ks[nxt + r1 * LDP + s0]) = n1;
        __syncthreads();
      }
    }
    // butterfly merge across the 16 lr-lanes (lg bits untouched)
#pragma unroll
    for (int msk = 1; msk <= 8; msk <<= 1) {
#pragma unroll
      for (int mt = 0; mt < 2; ++mt)
#pragma unroll
        for (int r = 0; r < 4; ++r) {
          float mo = __shfl_xor(m[mt][r], msk);
          float lo = __shfl_xor(l[mt][r], msk);
          float mn = fmaxf(m[mt][r], mo);
          l[mt][r] = l[mt][r] * exp2g(m[mt][r] - mn) + lo * exp2g(mo - mn);
          m[mt][r] = mn;
        }
    }
    if (lr == 0) {
#pragma unroll
      for (int mt = 0; mt < 2; ++mt)
#pragma unroll
        for (int r = 0; r < 4; ++r) {
          int q = q0 + wave * 32 + mt * 16 + lg * 4 + r;
          part[(sp * HH + h) * NN + q] = make_float2(m[mt][r], l[mt][r]);
        }
    }
  }
  gbar(&bar[48], t);

  // ---------------- phase 3: merge splits + global sum ----------------
  if (blk < 96) {
    float* wsum = (float*)smem_raw;
    const int row = blk * 256 + t;                 // 0..24575 = h*2048+q
    float2 p0 = part[row];
    float2 p1 = part[24576 + row];
    float2 p2 = part[49152 + row];
    float2 p3 = part[73728 + row];
    float mm = fmaxf(fmaxf(p0.x, p1.x), fmaxf(p2.x, p3.x));
    float ll = p0.y * exp2g(p0.x - mm) + p1.y * exp2g(p1.x - mm) +
               p2.y * exp2g(p2.x - mm) + p3.y * exp2g(p3.x - mm);
    float lse = mm + log2g(ll);                    // base-2 lse
#pragma unroll
    for (int msk = 1; msk <= 32; msk <<= 1)
      lse += __shfl_xor(lse, msk);
    if (lane == 0) wsum[wave] = lse;
    __syncthreads();
    if (t == 0)
      atomicAdd(out, -5.545177444479562f * (wsum[0] + wsum[1] + wsum[2] + wsum[3]));
  }
}

// ---------------- launch -----------------------------------------------------
extern "C" void kernel_launch(void* const* d_in, const int* in_sizes, int n_in,
                              void* d_out, int out_size, void* d_ws, size_t ws_size,
                              hipStream_t stream) {
  const float* g  = (const float*)d_in[0];
  const float* Wq = (const float*)d_in[1];
  const float* Wk = (const float*)d_in[2];
  float* out = (float*)d_out;

  char* ws = (char*)d_ws;
  __hip_bfloat16* gB = (__hip_bfloat16*)ws;                    // 3.1 MB
  __hip_bfloat16* wB = (__hip_bfloat16*)(ws + 3145728);        // 2.4 MB
  __hip_bfloat16* QK = (__hip_bfloat16*)(ws + 5505024);        // 6.3 MB
  float2* part = (float2*)(ws + 11796480);                     // 786 KB
  unsigned* bar = (unsigned*)(ws + 12582912);                  // barrier state

  mega_kernel<<<NBLK, 256, 0, stream>>>(g, Wq, Wk, gB, wB, QK, part, bar, out);
}

// Round 9
// 95.812 us; speedup vs baseline: 4.3254x; 3.6021x over previous
//
#include <hip/hip_runtime.h>
#include <hip/hip_bf16.h>

// N=2048, D=768, H=12, Y=64. W = [Wq;Wk] as [1536][768].
#define NN 2048
#define DD 768
#define HH 12
#define HW 1536
#define SPLITS 4
#define KPW (NN/SPLITS)           // 512 k-rows per split
#define NCH (KPW/64)              // 8 chunks per split
#define LDP 72                    // 64 + 8 pad -> 2-way max on frag reads (free)

typedef __attribute__((ext_vector_type(8))) short bf16x8;
typedef __attribute__((ext_vector_type(4))) float f32x4;

// native v_exp_f32 / v_log_f32 (both base-2). __exp2f/__log2f collide with
// glibc math.h reserved identifiers under -x hip.
__device__ __forceinline__ float exp2g(float x) { return __builtin_amdgcn_exp2f(x); }
__device__ __forceinline__ float log2g(float x) { return __builtin_amdgcn_logf(x); }

// Fold beta*log2(e) = 0.125*1.4426950408889634 into Wq -> scores in base-2.
#define QSCALE 0.18033688011112042f

__device__ __forceinline__ short b16(float x) {
  __hip_bfloat16 h = __float2bfloat16(x);
  return *reinterpret_cast<short*>(&h);
}
__device__ __forceinline__ bf16x8 cvt8(float4 a, float4 b, float sc) {
  bf16x8 r;
  r[0] = b16(a.x * sc); r[1] = b16(a.y * sc);
  r[2] = b16(a.z * sc); r[3] = b16(a.w * sc);
  r[4] = b16(b.x * sc); r[5] = b16(b.y * sc);
  r[6] = b16(b.z * sc); r[7] = b16(b.w * sc);
  return r;
}

// ---------------- Kernel 1: fused convert + projection GEMM ------------------
// QK[2048][1536] = g[2048][768](fp32) * W[1536][768](fp32)^T, cast via bf16.
// W rows 0..767 = Wq (scaled by QSCALE), 768..1535 = Wk. Staging loads fp32
// directly (L3-cached), converts in-register during ds_write -> no separate
// convert kernel, no bf16 copies of g/W in workspace.
// 64x64 tile, BK=64, grid (32,24)=768 (3/CU), double-buffered, 1 barrier/kt.
__global__ __launch_bounds__(256) void proj_kernel(
    const float* __restrict__ g, const float* __restrict__ Wq,
    const float* __restrict__ Wk, __hip_bfloat16* __restrict__ QK,
    float* __restrict__ out) {
  __shared__ __align__(16) __hip_bfloat16 As[2][64 * LDP];
  __shared__ __align__(16) __hip_bfloat16 Bs[2][64 * LDP];
  const int t = threadIdx.x;
  const int wave = t >> 6, lane = t & 63;
  const int lr = lane & 15, lg = lane >> 4;
  const int wm = wave & 1, wn = wave >> 1;
  const int bm = blockIdx.x, bn = blockIdx.y;
  if (bm == 0 && bn == 0 && t == 0) out[0] = 0.0f;   // for reduce's atomicAdd

  // W source rows for this bn-tile (wave-uniform select + scale)
  const float* Wsrc = (bn < 12) ? (Wq + bn * 64 * DD) : (Wk + (bn - 12) * 64 * DD);
  const float sc = (bn < 12) ? QSCALE : 1.0f;

  // staging coords: each thread covers rows r0, r0+32 at 8 fp32 cols s0c..+7
  const int r0 = t >> 3, s0c = (t & 7) * 8;
  const int r1 = r0 + 32;

  f32x4 acc[2][2] = {};

  // prologue: stage kt=0
  {
    const float* ga0 = g + (bm * 64 + r0) * DD + s0c;
    const float* ga1 = g + (bm * 64 + r1) * DD + s0c;
    const float* gb0 = Wsrc + r0 * DD + s0c;
    const float* gb1 = Wsrc + r1 * DD + s0c;
    *reinterpret_cast<bf16x8*>(&As[0][r0 * LDP + s0c]) =
        cvt8(*(const float4*)ga0, *(const float4*)(ga0 + 4), 1.0f);
    *reinterpret_cast<bf16x8*>(&As[0][r1 * LDP + s0c]) =
        cvt8(*(const float4*)ga1, *(const float4*)(ga1 + 4), 1.0f);
    *reinterpret_cast<bf16x8*>(&Bs[0][r0 * LDP + s0c]) =
        cvt8(*(const float4*)gb0, *(const float4*)(gb0 + 4), sc);
    *reinterpret_cast<bf16x8*>(&Bs[0][r1 * LDP + s0c]) =
        cvt8(*(const float4*)gb1, *(const float4*)(gb1 + 4), sc);
  }
  __syncthreads();

  for (int it = 0; it < 12; ++it) {
    const int cur = it & 1;
    float4 pa0, pa1, pa2, pa3, pb0, pb1, pb2, pb3;
    if (it < 11) {
      int kt = (it + 1) * 64;
      const float* ga0 = g + (bm * 64 + r0) * DD + kt + s0c;
      const float* ga1 = g + (bm * 64 + r1) * DD + kt + s0c;
      const float* gb0 = Wsrc + r0 * DD + kt + s0c;
      const float* gb1 = Wsrc + r1 * DD + kt + s0c;
      pa0 = *(const float4*)ga0; pa1 = *(const float4*)(ga0 + 4);
      pa2 = *(const float4*)ga1; pa3 = *(const float4*)(ga1 + 4);
      pb0 = *(const float4*)gb0; pb1 = *(const float4*)(gb0 + 4);
      pb2 = *(const float4*)gb1; pb3 = *(const float4*)(gb1 + 4);
    }
#pragma unroll
    for (int ks = 0; ks < 2; ++ks) {
      bf16x8 a[2], b[2];
#pragma unroll
      for (int mt = 0; mt < 2; ++mt)
        a[mt] = *reinterpret_cast<const bf16x8*>(&As[cur][(wm * 32 + mt * 16 + lr) * LDP + ks * 32 + lg * 8]);
#pragma unroll
      for (int nt = 0; nt < 2; ++nt)
        b[nt] = *reinterpret_cast<const bf16x8*>(&Bs[cur][(wn * 32 + nt * 16 + lr) * LDP + ks * 32 + lg * 8]);
#pragma unroll
      for (int mt = 0; mt < 2; ++mt)
#pragma unroll
        for (int nt = 0; nt < 2; ++nt)
          acc[mt][nt] = __builtin_amdgcn_mfma_f32_16x16x32_bf16(a[mt], b[nt], acc[mt][nt], 0, 0, 0);
    }
    if (it < 11) {
      const int nxt = cur ^ 1;
      *reinterpret_cast<bf16x8*>(&As[nxt][r0 * LDP + s0c]) = cvt8(pa0, pa1, 1.0f);
      *reinterpret_cast<bf16x8*>(&As[nxt][r1 * LDP + s0c]) = cvt8(pa2, pa3, 1.0f);
      *reinterpret_cast<bf16x8*>(&Bs[nxt][r0 * LDP + s0c]) = cvt8(pb0, pb1, sc);
      *reinterpret_cast<bf16x8*>(&Bs[nxt][r1 * LDP + s0c]) = cvt8(pb2, pb3, sc);
      __syncthreads();
    }
  }
#pragma unroll
  for (int mt = 0; mt < 2; ++mt) {
    int row = bm * 64 + wm * 32 + mt * 16 + lg * 4;
#pragma unroll
    for (int nt = 0; nt < 2; ++nt) {
      int col = bn * 64 + wn * 32 + nt * 16 + lr;
#pragma unroll
      for (int r = 0; r < 4; ++r)
        QK[(row + r) * HW + col] = __float2bfloat16(acc[mt][nt][r]);
    }
  }
}

// ---------------- Kernel 2: scores + per-lane online LSE, dbuf K -------------
// grid (16 q-tiles of 128, 12 heads, 4 k-splits) = 768 blocks (3/CU).
// Wave w owns q rows q0+w*32..+31. Q frags loaded ONCE direct from global;
// K staged in double-buffered LDS shared by all 4 waves, ONE barrier/chunk.
// Each lane keeps private (m,l) over its k-subset (k = kc+nt*16+lr).
__global__ __launch_bounds__(256) void attn_kernel(
    const __hip_bfloat16* __restrict__ QK, float2* __restrict__ part) {
  __shared__ __align__(16) __hip_bfloat16 Ks[2][64 * LDP];
  const int t = threadIdx.x;
  const int wave = t >> 6, lane = t & 63;
  const int lr = lane & 15, lg = lane >> 4;
  const int q0 = blockIdx.x * 128, h = blockIdx.y, sp = blockIdx.z;
  const int k0 = sp * KPW;
  const int r0 = t >> 3, s0 = (t & 7) * 8;
  const int r1 = r0 + 32;
  const int colK = DD + h * 64;

  // Q fragments: 4 direct loads, resident for the whole kernel
  bf16x8 aq[2][2];
#pragma unroll
  for (int mt = 0; mt < 2; ++mt)
#pragma unroll
    for (int z = 0; z < 2; ++z)
      aq[mt][z] = *reinterpret_cast<const bf16x8*>(
          QK + (q0 + wave * 32 + mt * 16 + lr) * HW + h * 64 + z * 32 + lg * 8);

  // prologue: stage chunk 0
  *reinterpret_cast<uint4*>(&Ks[0][r0 * LDP + s0]) =
      *reinterpret_cast<const uint4*>(QK + (k0 + r0) * HW + colK + s0);
  *reinterpret_cast<uint4*>(&Ks[0][r1 * LDP + s0]) =
      *reinterpret_cast<const uint4*>(QK + (k0 + r1) * HW + colK + s0);
  __syncthreads();

  float m[2][4], l[2][4];
#pragma unroll
  for (int mt = 0; mt < 2; ++mt)
#pragma unroll
    for (int r = 0; r < 4; ++r) { m[mt][r] = -3.0e38f; l[mt][r] = 0.0f; }

  for (int ci = 0; ci < NCH; ++ci) {
    const int cur = ci & 1;
    uint4 n0, n1;
    if (ci < NCH - 1) {
      int kc = k0 + (ci + 1) * 64;
      n0 = *reinterpret_cast<const uint4*>(QK + (kc + r0) * HW + colK + s0);
      n1 = *reinterpret_cast<const uint4*>(QK + (kc + r1) * HW + colK + s0);
    }
    bf16x8 b[4][2];
#pragma unroll
    for (int nt = 0; nt < 4; ++nt)
#pragma unroll
      for (int z = 0; z < 2; ++z)
        b[nt][z] = *reinterpret_cast<const bf16x8*>(&Ks[cur][(nt * 16 + lr) * LDP + z * 32 + lg * 8]);

    f32x4 s[2][4] = {};
#pragma unroll
    for (int mt = 0; mt < 2; ++mt)
#pragma unroll
      for (int nt = 0; nt < 4; ++nt)
#pragma unroll
        for (int z = 0; z < 2; ++z)
          s[mt][nt] = __builtin_amdgcn_mfma_f32_16x16x32_bf16(aq[mt][z], b[nt][z], s[mt][nt], 0, 0, 0);

    // per-lane online update (scores already in base-2 units)
#pragma unroll
    for (int mt = 0; mt < 2; ++mt)
#pragma unroll
      for (int r = 0; r < 4; ++r) {
        float v0 = s[mt][0][r], v1 = s[mt][1][r], v2 = s[mt][2][r], v3 = s[mt][3][r];
        float cm = fmaxf(fmaxf(v0, v1), fmaxf(v2, v3));
        float mn = fmaxf(m[mt][r], cm);
        float p = exp2g(v0 - mn) + exp2g(v1 - mn) +
                  exp2g(v2 - mn) + exp2g(v3 - mn);
        l[mt][r] = l[mt][r] * exp2g(m[mt][r] - mn) + p;
        m[mt][r] = mn;
      }
    if (ci < NCH - 1) {
      *reinterpret_cast<uint4*>(&Ks[cur ^ 1][r0 * LDP + s0]) = n0;
      *reinterpret_cast<uint4*>(&Ks[cur ^ 1][r1 * LDP + s0]) = n1;
      __syncthreads();
    }
  }
  // butterfly merge across the 16 lr-lanes (lg bits untouched)
#pragma unroll
  for (int msk = 1; msk <= 8; msk <<= 1) {
#pragma unroll
    for (int mt = 0; mt < 2; ++mt)
#pragma unroll
      for (int r = 0; r < 4; ++r) {
        float mo = __shfl_xor(m[mt][r], msk);
        float lo = __shfl_xor(l[mt][r], msk);
        float mn = fmaxf(m[mt][r], mo);
        l[mt][r] = l[mt][r] * exp2g(m[mt][r] - mn) + lo * exp2g(mo - mn);
        m[mt][r] = mn;
      }
  }
  if (lr == 0) {
#pragma unroll
    for (int mt = 0; mt < 2; ++mt)
#pragma unroll
      for (int r = 0; r < 4; ++r) {
        int q = q0 + wave * 32 + mt * 16 + lg * 4 + r;
        part[(sp * HH + h) * NN + q] = make_float2(m[mt][r], l[mt][r]);
      }
  }
}

// ---------------- Kernel 3: merge splits + global sum ------------------------
// 24 blocks x 1024 thr, one row each; out zeroed by proj_kernel.
__global__ __launch_bounds__(1024) void reduce_kernel(
    const float2* __restrict__ part, float* __restrict__ out) {
  const int t = threadIdx.x;
  const int row = blockIdx.x * 1024 + t;         // 0..24575 = (h*2048+q)
  float2 p0 = part[row];
  float2 p1 = part[24576 + row];
  float2 p2 = part[49152 + row];
  float2 p3 = part[73728 + row];
  float mm = fmaxf(fmaxf(p0.x, p1.x), fmaxf(p2.x, p3.x));
  float ll = p0.y * exp2g(p0.x - mm) + p1.y * exp2g(p1.x - mm) +
             p2.y * exp2g(p2.x - mm) + p3.y * exp2g(p3.x - mm);
  float lse = mm + log2g(ll);                    // base-2 lse
#pragma unroll
  for (int msk = 1; msk <= 32; msk <<= 1)
    lse += __shfl_xor(lse, msk);
  __shared__ float wsum[16];
  if ((t & 63) == 0) wsum[t >> 6] = lse;
  __syncthreads();
  if (t == 0) {
    float s = 0.0f;
#pragma unroll
    for (int i = 0; i < 16; ++i) s += wsum[i];
    atomicAdd(out, -5.545177444479562f * s);     // -(1/beta)*ln2 * sum(lse2)
  }
}

// ---------------- launch -----------------------------------------------------
extern "C" void kernel_launch(void* const* d_in, const int* in_sizes, int n_in,
                              void* d_out, int out_size, void* d_ws, size_t ws_size,
                              hipStream_t stream) {
  const float* g  = (const float*)d_in[0];
  const float* Wq = (const float*)d_in[1];
  const float* Wk = (const float*)d_in[2];
  float* out = (float*)d_out;

  char* ws = (char*)d_ws;
  __hip_bfloat16* QK = (__hip_bfloat16*)ws;              // [2048][1536] 6.3 MB
  float2* part = (float2*)(ws + 6291456);                // [4][12][2048] 786 KB

  proj_kernel<<<dim3(32, 24), 256, 0, stream>>>(g, Wq, Wk, QK, out);
  attn_kernel<<<dim3(16, HH, SPLITS), 256, 0, stream>>>(QK, part);
  reduce_kernel<<<24, 1024, 0, stream>>>(part, out);
}